// Round 9
// baseline (68.038 us; speedup 1.0000x reference)
//
#include <hip/hip_runtime.h>
#include <math.h>

#define NB_TOTAL 65536
#define NOBS 256
#define OUTS 773            // 2 + 514 + 257

typedef float f32x4 __attribute__((ext_vector_type(4)));
typedef float f32x2 __attribute__((ext_vector_type(2)));

// Output row layout (f32):
//  [0..1] x31 | [2+i] G flat i=2j+comp (j obst, 512 vals) | [514,515] G_o
//  [516+j] h_s | [772] h_o
//
// prm row layout (16 f32):
//  [0]A0 [1]tvs [2]tvc [3]A1 | [4]tc [5]ts [6]x31_0 [7]x31_1
//  [8]Go0 [9]Go1 [10]ho [11]- | [12]C [13]u [14]w [15]pp
//  G0(j) = A0 - tvs*ox + tvc*oy ; G1(j) = A1 + tc*ox + ts*oy
//  h(j)  = C + u*ox + w*oy + pp*q ; q = ox^2+oy^2-R^2
//
// Phase B: row base dword = row*773; ph = row & 3 (773 ≡ 1 mod 4) is
// COMPILE-TIME per unrolled sub-iteration. Lane l stores aligned chunks
// k = l+1, l+65, l+129 (global dwords a0 + 4k..4k+3, a0 = base - ph),
// values computed directly in registers from phase-shifted obstacle
// features. Boundary straddles handled by per-lane overrides.
// R7 lesson: only 16B-ALIGNED dwordx4 stores are safe — these all are.

template<int PH>
__device__ __forceinline__ void row_store(
    int row, int rloc, int l,
    const float (&prm)[64][16],
    const float (&ax)[4], const float (&ay)[4],      // obstacles 2l-1..2l+2
    const float (&bx)[4], const float (&by)[4],      // obstacles 2l+127..2l+130
    const float (&cx)[7], const float (&cy)[7], const float (&cq)[7], // 4l-3..4l+3
    float o0x, float o0y, float e255x, float e255y,  // obst 0, obst 255
    const float (&tx)[3], const float (&ty)[3], const float (&tq)[3], // obst 253..255
    float* __restrict__ out)
{
    const f32x4 c0 = *(const f32x4*)&prm[rloc][0];
    const f32x4 c1 = *(const f32x4*)&prm[rloc][4];
    const f32x4 c2 = *(const f32x4*)&prm[rloc][8];
    const f32x4 c3 = *(const f32x4*)&prm[rloc][12];
    const float A0 = c0.x, tvs = c0.y, tvc = c0.z, A1 = c0.w;
    const float tc = c1.x, ts  = c1.y, x31_0 = c1.z, x31_1 = c1.w;
    const float Go0 = c2.x, Go1 = c2.y, ho = c2.z;
    const float C = c3.x, u = c3.y, w = c3.z, pp = c3.w;

    auto G0 = [&](float X, float Y) { return fmaf(Y, tvc, fmaf(-X, tvs, A0)); };
    auto G1 = [&](float X, float Y) { return fmaf(Y, ts,  fmaf( X, tc,  A1)); };
    auto H  = [&](float X, float Y, float Q) {
        return fmaf(pp, Q, fmaf(w, Y, fmaf(u, X, C)));
    };

    const unsigned base = (unsigned)row * 773u;
    float* a0p = out + (base - (unsigned)PH);        // 16B-aligned

    // ---- chunk A: k = l+1, f = 4l+4-PH+t, G flat i = 4l+2-PH+t ----------
    f32x4 vA;
    if (PH == 0) vA = (f32x4){G0(ax[2],ay[2]), G1(ax[2],ay[2]), G0(ax[3],ay[3]), G1(ax[3],ay[3])};
    if (PH == 1) vA = (f32x4){G1(ax[1],ay[1]), G0(ax[2],ay[2]), G1(ax[2],ay[2]), G0(ax[3],ay[3])};
    if (PH == 2) vA = (f32x4){G0(ax[1],ay[1]), G1(ax[1],ay[1]), G0(ax[2],ay[2]), G1(ax[2],ay[2])};
    if (PH == 3) vA = (f32x4){G1(ax[0],ay[0]), G0(ax[1],ay[1]), G1(ax[1],ay[1]), G0(ax[2],ay[2])};
    if (PH == 3 && l == 0) vA.x = x31_1;             // f=1
    *(f32x4*)(a0p + 4 * (l + 1)) = vA;

    // ---- chunk B: k = l+65, G flat i = 4l+258-PH+t -----------------------
    f32x4 vB;
    if (PH == 0) vB = (f32x4){G0(bx[2],by[2]), G1(bx[2],by[2]), G0(bx[3],by[3]), G1(bx[3],by[3])};
    if (PH == 1) vB = (f32x4){G1(bx[1],by[1]), G0(bx[2],by[2]), G1(bx[2],by[2]), G0(bx[3],by[3])};
    if (PH == 2) vB = (f32x4){G0(bx[1],by[1]), G1(bx[1],by[1]), G0(bx[2],by[2]), G1(bx[2],by[2])};
    if (PH == 3) vB = (f32x4){G1(bx[0],by[0]), G0(bx[1],by[1]), G1(bx[1],by[1]), G0(bx[2],by[2])};
    if (l == 63) {                                   // i>=512 -> Go
        if (PH == 0) { vB.z = Go0; vB.w = Go1; }
        if (PH == 1) { vB.w = Go0; }
    }
    *(f32x4*)(a0p + 4 * (l + 65)) = vB;

    // ---- chunk C: k = l+129, h idx m = 4l-PH+t ---------------------------
    f32x4 vC;
    if (PH == 0) vC = (f32x4){H(cx[3],cy[3],cq[3]), H(cx[4],cy[4],cq[4]), H(cx[5],cy[5],cq[5]), H(cx[6],cy[6],cq[6])};
    if (PH == 1) vC = (f32x4){H(cx[2],cy[2],cq[2]), H(cx[3],cy[3],cq[3]), H(cx[4],cy[4],cq[4]), H(cx[5],cy[5],cq[5])};
    if (PH == 2) vC = (f32x4){H(cx[1],cy[1],cq[1]), H(cx[2],cy[2],cq[2]), H(cx[3],cy[3],cq[3]), H(cx[4],cy[4],cq[4])};
    if (PH == 3) vC = (f32x4){H(cx[0],cy[0],cq[0]), H(cx[1],cy[1],cq[1]), H(cx[2],cy[2],cq[2]), H(cx[3],cy[3],cq[3])};
    if (l == 0) {                                    // m<0 -> G511/Go
        if (PH == 1) { vC.x = Go1; }
        if (PH == 2) { vC.x = Go0; vC.y = Go1; }
        if (PH == 3) { vC.x = G1(e255x, e255y); vC.y = Go0; vC.z = Go1; }
    }
    *(f32x4*)(a0p + 4 * (l + 129)) = vC;

    // ---- head chunk k=0 (lane 0): f = t-PH -------------------------------
    if (l == 0) {
        if (PH == 0) {
            *(f32x4*)a0p = (f32x4){x31_0, x31_1, G0(o0x, o0y), G1(o0x, o0y)};
        } else if (PH == 1) {
            a0p[1] = x31_0;
            *(f32x2*)(a0p + 2) = (f32x2){x31_1, G0(o0x, o0y)};
        } else if (PH == 2) {
            *(f32x2*)(a0p + 2) = (f32x2){x31_0, x31_1};
        } else {
            a0p[3] = x31_0;
        }
    }
    // ---- tail chunk k=193 (lane 1): f = 772-PH+t -------------------------
    else if (l == 1) {
        float* tp = a0p + 772;                       // 16B-aligned
        if (PH == 0) {
            tp[0] = ho;
        } else if (PH == 1) {
            *(f32x2*)tp = (f32x2){H(tx[2],ty[2],tq[2]), ho};
        } else if (PH == 2) {
            *(f32x2*)tp = (f32x2){H(tx[1],ty[1],tq[1]), H(tx[2],ty[2],tq[2])};
            tp[2] = ho;
        } else {
            *(f32x4*)tp = (f32x4){H(tx[0],ty[0],tq[0]), H(tx[1],ty[1],tq[1]),
                                  H(tx[2],ty[2],tq[2]), ho};
        }
    }
}

__global__ __launch_bounds__(256, 4) void fused3(
    const float* __restrict__ x,
    const float* __restrict__ obstacles,
    const float* __restrict__ input_mean, const float* __restrict__ input_std,
    const float* __restrict__ W1,  const float* __restrict__ b1,
    const float* __restrict__ W21, const float* __restrict__ b21,
    const float* __restrict__ W22, const float* __restrict__ b22,
    const float* __restrict__ W31, const float* __restrict__ b31,
    const float* __restrict__ W32, const float* __restrict__ b32,
    float* __restrict__ out)
{
    __shared__ float pacc[2][64][33];   // partial acc exchange (+1 pad)
    __shared__ float prm[64][16];       // per-row coefficients

    const int tid  = threadIdx.x;
    const int l    = tid & 63;
    const int wv   = __builtin_amdgcn_readfirstlane(tid >> 6);
    const int role = wv & 1;
    const int half = wv >> 1;
    const int row  = blockIdx.x * 64 + l;

    // ======================= Phase A: MLP + coefficients (R8, proven) ======
    float xr[8];
    {
        const float4 xa = *(const float4*)(x + (size_t)row * 8);
        const float4 xb = *(const float4*)(x + (size_t)row * 8 + 4);
        xr[0]=xa.x; xr[1]=xa.y; xr[2]=xa.z; xr[3]=xa.w;
        xr[4]=xb.x; xr[5]=xb.y; xr[6]=xb.z; xr[7]=xb.w;
    }

    const float* Wh = role ? W22 : W21;
    const float* bh = role ? b22 : b21;

    float acc[32];
    #pragma unroll
    for (int k = 0; k < 32; ++k) acc[k] = half ? 0.0f : bh[k];

    const int ibeg = half * 64;
    #pragma unroll 1
    for (int i0 = ibeg; i0 < ibeg + 64; i0 += 8) {
        float hh[8];
        #pragma unroll
        for (int u = 0; u < 8; ++u) {
            float a = b1[i0 + u];
            #pragma unroll
            for (int k = 0; k < 8; ++k)
                a = fmaf(xr[k], W1[k * 128 + i0 + u], a);
            hh[u] = fmaxf(a, 0.0f);
        }
        #pragma unroll
        for (int u = 0; u < 8; ++u) {
            #pragma unroll
            for (int k = 0; k < 32; ++k)
                acc[k] = fmaf(hh[u], Wh[(i0 + u) * 32 + k], acc[k]);
        }
    }

    if (half == 0) {
        #pragma unroll
        for (int k = 0; k < 32; ++k) pacc[role][l][k] = acc[k];
    }
    __syncthreads();

    if (half == 1) {
        #pragma unroll
        for (int k = 0; k < 32; ++k) acc[k] += pacc[role][l][k];

        const float* Wo = role ? W32 : W31;
        const float* bo = role ? b32 : b31;
        float o0 = bo[0], o1 = bo[1];
        #pragma unroll
        for (int k = 0; k < 32; ++k) {
            float a = fmaxf(acc[k], 0.0f);
            o0 = fmaf(a, Wo[k * 2 + 0], o0);
            o1 = fmaf(a, Wo[k * 2 + 1], o1);
        }

        float x0v[8];
        #pragma unroll
        for (int k = 0; k < 8; ++k)
            x0v[k] = fmaf(xr[k], input_std[k], input_mean[k]);
        const float px = x0v[0], py = x0v[1], th = x0v[2], v = x0v[3];
        const float opx = x0v[4], opy = x0v[5], oth = x0v[6], ov = x0v[7];

        float st, ct, sto, cto;
        sincosf(th,  &st,  &ct);
        sincosf(oth, &sto, &cto);

        const float tvs = 2.0f * v * st;
        const float tvc = 2.0f * v * ct;
        const float tc  = 2.0f * ct;
        const float ts  = 2.0f * st;
        const float hc  = 2.0f * v * v;

        const float dxo = px - opx, dyo = py - opy;

        if (role == 0) {
            const float A0  = px * tvs - py * tvc;
            const float A1  = -(px * tc + py * ts);
            const float Go0 = dxo * tvs - dyo * tvc;
            const float Go1 = -(dxo * tc + dyo * ts);
            *(f32x4*)&prm[l][0] = (f32x4){A0, tvs, tvc, A1};
            *(f32x4*)&prm[l][4] = (f32x4){tc, ts, o0, o1};
            *(f32x2*)&prm[l][8] = (f32x2){Go0, Go1};
        } else {
            const float p0 = 4.0f / (1.0f + __expf(-o0));
            const float p1 = 4.0f / (1.0f + __expf(-o1));
            const float ps = p0 + p1;
            const float pp = p0 * p1;
            const float B0 = px * tvc + py * tvs;
            const float C  = hc + ps * B0 + pp * (px * px + py * py);
            const float u  = -(ps * tvc) - 2.0f * pp * px;
            const float w  = -(ps * tvs) - 2.0f * pp * py;
            const float ob  = dxo * dxo + dyo * dyo - 1.21f;     // Ro^2
            const float rvx = v * ct - ov * cto;
            const float rvy = v * st - ov * sto;
            const float obd = 2.0f * (dxo * rvx + dyo * rvy);
            const float cth_sum = ct * cto - st * sto;            // cos(th+oth)
            const float oLf2b = 2.0f * (v * v + ov * ov - 2.0f * v * ov * cth_sum);
            const float ho = oLf2b + ps * obd + pp * ob;
            *(f32x2*)&prm[l][10]  = (f32x2){ho, 0.0f};
            *(f32x4*)&prm[l][12]  = (f32x4){C, u, w, pp};
        }
    }

    // ---- obstacle features (registers), loaded while prm settles ---------
    float ax[4], ay[4];                  // obstacles 2l-1 .. 2l+2
    #pragma unroll
    for (int c = 0; c < 4; ++c) {
        const int j = max(2 * l - 1 + c, 0);
        const float* o = obstacles + (size_t)j * 3;
        ax[c] = o[0]; ay[c] = o[1];
    }
    float bx[4], by[4];                  // obstacles 2l+127 .. 2l+130
    #pragma unroll
    for (int c = 0; c < 4; ++c) {
        const int j = min(2 * l + 127 + c, 255);
        const float* o = obstacles + (size_t)j * 3;
        bx[c] = o[0]; by[c] = o[1];
    }
    float cx[7], cy[7], cq[7];           // obstacles 4l-3 .. 4l+3
    #pragma unroll
    for (int c = 0; c < 7; ++c) {
        const int j = min(max(4 * l - 3 + c, 0), 255);
        const float* o = obstacles + (size_t)j * 3;
        const float a = o[0], b = o[1], r = o[2] + 0.6f;  // R = 0.5+rad+0.1
        cx[c] = a; cy[c] = b; cq[c] = fmaf(a, a, b * b) - r * r;
    }
    // uniform specials: obst 0, obst 255 (x,y); obst 253..255 (x,y,q)
    const float o0x = obstacles[0], o0y = obstacles[1];
    const float e255x = obstacles[255 * 3], e255y = obstacles[255 * 3 + 1];
    float tx[3], ty[3], tq[3];
    #pragma unroll
    for (int c = 0; c < 3; ++c) {
        const float* o = obstacles + (size_t)(253 + c) * 3;
        const float a = o[0], b = o[1], r = o[2] + 0.6f;
        tx[c] = a; ty[c] = b; tq[c] = fmaf(a, a, b * b) - r * r;
    }

    __syncthreads();

    // ======================= Phase B: direct aligned stores ================
    const int blockRow0 = blockIdx.x * 64;
    #pragma unroll 1
    for (int g = 0; g < 4; ++g) {
        const int r0 = wv * 16 + g * 4;
        row_store<0>(blockRow0 + r0 + 0, r0 + 0, l, prm, ax, ay, bx, by,
                     cx, cy, cq, o0x, o0y, e255x, e255y, tx, ty, tq, out);
        row_store<1>(blockRow0 + r0 + 1, r0 + 1, l, prm, ax, ay, bx, by,
                     cx, cy, cq, o0x, o0y, e255x, e255y, tx, ty, tq, out);
        row_store<2>(blockRow0 + r0 + 2, r0 + 2, l, prm, ax, ay, bx, by,
                     cx, cy, cq, o0x, o0y, e255x, e255y, tx, ty, tq, out);
        row_store<3>(blockRow0 + r0 + 3, r0 + 3, l, prm, ax, ay, bx, by,
                     cx, cy, cq, o0x, o0y, e255x, e255y, tx, ty, tq, out);
    }
}

extern "C" void kernel_launch(void* const* d_in, const int* in_sizes, int n_in,
                              void* d_out, int out_size, void* d_ws, size_t ws_size,
                              hipStream_t stream) {
    const float* x          = (const float*)d_in[0];
    const float* obstacles  = (const float*)d_in[1];
    const float* input_mean = (const float*)d_in[2];
    const float* input_std  = (const float*)d_in[3];
    const float* W1  = (const float*)d_in[4];
    const float* b1  = (const float*)d_in[5];
    const float* W21 = (const float*)d_in[6];
    const float* b21 = (const float*)d_in[7];
    const float* W22 = (const float*)d_in[8];
    const float* b22 = (const float*)d_in[9];
    const float* W31 = (const float*)d_in[10];
    const float* b31 = (const float*)d_in[11];
    const float* W32 = (const float*)d_in[12];
    const float* b32 = (const float*)d_in[13];

    float* out = (float*)d_out;

    fused3<<<dim3(NB_TOTAL / 64), dim3(256), 0, stream>>>(
        x, obstacles, input_mean, input_std,
        W1, b1, W21, b21, W22, b22, W31, b31, W32, b32, out);
}

// Round 10
// 50.854 us; speedup vs baseline: 1.3379x; 1.3379x over previous
//
#include <hip/hip_runtime.h>
#include <math.h>

#define NB_TOTAL 65536
#define OUTS 773            // 2 + 514 + 257

typedef float f32x4 __attribute__((ext_vector_type(4)));
typedef float f32x2 __attribute__((ext_vector_type(2)));

// Output row layout (f32):
//  [0..1] x31 | [2+i] G flat i=2j+comp (512 vals) | [514,515] G_o
//  [516+m] h_s | [772] h_o
//
// prm row layout (16 f32):
//  [0]A0 [1]tvs [2]tvc [3]A1 | [4]tc [5]ts [6]x31_0 [7]x31_1
//  [8]Go0 [9]Go1 [10]ho [11]- | [12]C [13]u [14]w [15]pp
//  G0(j) = A0 - tvs*ox + tvc*oy ; G1(j) = A1 + tc*ox + ts*oy
//  h(m)  = C + u*ox + w*oy + pp*q ; q = ox^2+oy^2-R^2
//
// Phase B (direct aligned stores): base = row*773; ph = row&3 (773≡1 mod 4).
// ONE PHASE PER WAVE: wave wv handles rows rloc = 4t+wv, so PH==wv is
// compile-time. Lane l stores chunks k=l+1 (G), l+65 (G), l+129 (h);
// lane0/lane1 handle head/tail chunks. All stores 16B-aligned (R7 lesson).
// R9 lesson: never keep >1 row's chunk values in flight (VGPR spill).

__device__ __forceinline__ int iclamp(int v, int lo, int hi) {
    return v < lo ? lo : (v > hi ? hi : v);
}

template<int PH>
__device__ __forceinline__ void phase_rows(
    int blockRow0, int l,
    const float (&prm)[64][16],
    const float* __restrict__ obstacles,
    float* __restrict__ out)
{
    // ---- per-phase obstacle features (registers) --------------------------
    // Chunk A uses G flat i = 4l+2-PH+t -> obstacles starting at 2l+aStart.
    constexpr int aStart = (PH == 0) ? 1 : (PH == 3 ? -1 : 0);
    constexpr int nA = (PH == 0 || PH == 2) ? 2 : 3;

    float Ax[3], Ay[3];
    #pragma unroll
    for (int c = 0; c < nA; ++c) {
        const int j = iclamp(2 * l + aStart + c, 0, 255);
        const float* o = obstacles + (size_t)j * 3;
        Ax[c] = o[0]; Ay[c] = o[1];
    }
    float Bx[3], By[3];
    #pragma unroll
    for (int c = 0; c < nA; ++c) {
        const int j = iclamp(2 * l + 128 + aStart + c, 0, 255);
        const float* o = obstacles + (size_t)j * 3;
        Bx[c] = o[0]; By[c] = o[1];
    }
    // Chunk C uses h index m = 4l-PH+t -> obstacles 4l-PH .. 4l-PH+3.
    float Cx[4], Cy[4], Cq[4];
    #pragma unroll
    for (int c = 0; c < 4; ++c) {
        const int j = iclamp(4 * l - PH + c, 0, 255);
        const float* o = obstacles + (size_t)j * 3;
        const float a = o[0], b = o[1], r = o[2] + 0.6f;  // R = 0.5+rad+0.1
        Cx[c] = a; Cy[c] = b; Cq[c] = fmaf(a, a, b * b) - r * r;
    }
    // specials
    float o0x = 0.f, o0y = 0.f, e255x = 0.f, e255y = 0.f;
    if (PH == 0 || PH == 1) { o0x = obstacles[0]; o0y = obstacles[1]; }
    if (PH == 3) { e255x = obstacles[255 * 3]; e255y = obstacles[255 * 3 + 1]; }
    float Tx[3], Ty[3], Tq[3];          // h[253..255] features (tail, lane 1)
    if (PH >= 1) {
        #pragma unroll
        for (int c = 0; c < 3; ++c) {
            const float* o = obstacles + (size_t)(253 + c) * 3;
            const float a = o[0], b = o[1], r = o[2] + 0.6f;
            Tx[c] = a; Ty[c] = b; Tq[c] = fmaf(a, a, b * b) - r * r;
        }
    }

    // ---- 16 rows, one per iteration (keep live-set to ONE row) ------------
    #pragma unroll 1
    for (int t = 0; t < 16; ++t) {
        const int rloc = 4 * t + PH;
        const int row  = blockRow0 + rloc;

        const f32x4 c0 = *(const f32x4*)&prm[rloc][0];
        const f32x4 c1 = *(const f32x4*)&prm[rloc][4];
        const f32x4 c2 = *(const f32x4*)&prm[rloc][8];
        const f32x4 c3 = *(const f32x4*)&prm[rloc][12];
        const float A0 = c0.x, tvs = c0.y, tvc = c0.z, A1 = c0.w;
        const float tc = c1.x, ts  = c1.y, x31_0 = c1.z, x31_1 = c1.w;
        const float Go0 = c2.x, Go1 = c2.y, ho = c2.z;
        const float C = c3.x, u = c3.y, w = c3.z, pp = c3.w;

        auto G0 = [&](float X, float Y) { return fmaf(Y, tvc, fmaf(-X, tvs, A0)); };
        auto G1 = [&](float X, float Y) { return fmaf(Y, ts,  fmaf( X, tc,  A1)); };
        auto H  = [&](float X, float Y, float Q) {
            return fmaf(pp, Q, fmaf(w, Y, fmaf(u, X, C)));
        };

        const unsigned base = (unsigned)row * 773u;
        float* a0p = out + (base - (unsigned)PH);        // 16B-aligned

        // chunk A: k = l+1
        f32x4 vA;
        if (PH == 0 || PH == 2)
            vA = (f32x4){G0(Ax[0],Ay[0]), G1(Ax[0],Ay[0]),
                         G0(Ax[1],Ay[1]), G1(Ax[1],Ay[1])};
        else
            vA = (f32x4){G1(Ax[0],Ay[0]), G0(Ax[1],Ay[1]),
                         G1(Ax[1],Ay[1]), G0(Ax[2],Ay[2])};
        if (PH == 3 && l == 0) vA.x = x31_1;             // f=1
        *(f32x4*)(a0p + 4 * (l + 1)) = vA;

        // chunk B: k = l+65
        f32x4 vB;
        if (PH == 0 || PH == 2)
            vB = (f32x4){G0(Bx[0],By[0]), G1(Bx[0],By[0]),
                         G0(Bx[1],By[1]), G1(Bx[1],By[1])};
        else
            vB = (f32x4){G1(Bx[0],By[0]), G0(Bx[1],By[1]),
                         G1(Bx[1],By[1]), G0(Bx[2],By[2])};
        if (l == 63) {                                   // i>=512 -> Go
            if (PH == 0) { vB.z = Go0; vB.w = Go1; }
            if (PH == 1) { vB.w = Go0; }
        }
        *(f32x4*)(a0p + 4 * (l + 65)) = vB;

        // chunk C: k = l+129
        f32x4 vC = (f32x4){H(Cx[0],Cy[0],Cq[0]), H(Cx[1],Cy[1],Cq[1]),
                           H(Cx[2],Cy[2],Cq[2]), H(Cx[3],Cy[3],Cq[3])};
        if (l == 0) {                                    // m<0 -> G511/Go
            if (PH == 1) { vC.x = Go1; }
            if (PH == 2) { vC.x = Go0; vC.y = Go1; }
            if (PH == 3) { vC.x = G1(e255x, e255y); vC.y = Go0; vC.z = Go1; }
        }
        *(f32x4*)(a0p + 4 * (l + 129)) = vC;

        // head chunk k=0 (lane 0): f = t-PH
        if (l == 0) {
            if (PH == 0) {
                *(f32x4*)a0p = (f32x4){x31_0, x31_1, G0(o0x,o0y), G1(o0x,o0y)};
            } else if (PH == 1) {
                a0p[1] = x31_0;
                *(f32x2*)(a0p + 2) = (f32x2){x31_1, G0(o0x,o0y)};
            } else if (PH == 2) {
                *(f32x2*)(a0p + 2) = (f32x2){x31_0, x31_1};
            } else {
                a0p[3] = x31_0;
            }
        }
        // tail chunk k=193 (lane 1): f = 772-PH+t
        else if (l == 1) {
            float* tp = a0p + 772;                       // 16B-aligned
            if (PH == 0) {
                tp[0] = ho;
            } else if (PH == 1) {
                *(f32x2*)tp = (f32x2){H(Tx[2],Ty[2],Tq[2]), ho};
            } else if (PH == 2) {
                *(f32x2*)tp = (f32x2){H(Tx[1],Ty[1],Tq[1]), H(Tx[2],Ty[2],Tq[2])};
                tp[2] = ho;
            } else {
                *(f32x4*)tp = (f32x4){H(Tx[0],Ty[0],Tq[0]), H(Tx[1],Ty[1],Tq[1]),
                                      H(Tx[2],Ty[2],Tq[2]), ho};
            }
        }
    }
}

__global__ __launch_bounds__(256, 4) void fused4(
    const float* __restrict__ x,
    const float* __restrict__ obstacles,
    const float* __restrict__ input_mean, const float* __restrict__ input_std,
    const float* __restrict__ W1,  const float* __restrict__ b1,
    const float* __restrict__ W21, const float* __restrict__ b21,
    const float* __restrict__ W22, const float* __restrict__ b22,
    const float* __restrict__ W31, const float* __restrict__ b31,
    const float* __restrict__ W32, const float* __restrict__ b32,
    float* __restrict__ out)
{
    __shared__ float pacc[2][64][33];   // partial acc exchange (+1 pad)
    __shared__ float prm[64][16];       // per-row coefficients

    const int tid  = threadIdx.x;
    const int l    = tid & 63;
    const int wv   = __builtin_amdgcn_readfirstlane(tid >> 6);
    const int role = wv & 1;
    const int half = wv >> 1;
    const int row  = blockIdx.x * 64 + l;

    // ======================= Phase A: MLP + coefficients (R8, proven) ======
    float xr[8];
    {
        const float4 xa = *(const float4*)(x + (size_t)row * 8);
        const float4 xb = *(const float4*)(x + (size_t)row * 8 + 4);
        xr[0]=xa.x; xr[1]=xa.y; xr[2]=xa.z; xr[3]=xa.w;
        xr[4]=xb.x; xr[5]=xb.y; xr[6]=xb.z; xr[7]=xb.w;
    }

    const float* Wh = role ? W22 : W21;
    const float* bh = role ? b22 : b21;

    float acc[32];
    #pragma unroll
    for (int k = 0; k < 32; ++k) acc[k] = half ? 0.0f : bh[k];

    const int ibeg = half * 64;
    #pragma unroll 1
    for (int i0 = ibeg; i0 < ibeg + 64; i0 += 8) {
        float hh[8];
        #pragma unroll
        for (int u = 0; u < 8; ++u) {
            float a = b1[i0 + u];
            #pragma unroll
            for (int k = 0; k < 8; ++k)
                a = fmaf(xr[k], W1[k * 128 + i0 + u], a);
            hh[u] = fmaxf(a, 0.0f);
        }
        #pragma unroll
        for (int u = 0; u < 8; ++u) {
            #pragma unroll
            for (int k = 0; k < 32; ++k)
                acc[k] = fmaf(hh[u], Wh[(i0 + u) * 32 + k], acc[k]);
        }
    }

    if (half == 0) {
        #pragma unroll
        for (int k = 0; k < 32; ++k) pacc[role][l][k] = acc[k];
    }
    __syncthreads();

    if (half == 1) {
        #pragma unroll
        for (int k = 0; k < 32; ++k) acc[k] += pacc[role][l][k];

        const float* Wo = role ? W32 : W31;
        const float* bo = role ? b32 : b31;
        float o0 = bo[0], o1 = bo[1];
        #pragma unroll
        for (int k = 0; k < 32; ++k) {
            float a = fmaxf(acc[k], 0.0f);
            o0 = fmaf(a, Wo[k * 2 + 0], o0);
            o1 = fmaf(a, Wo[k * 2 + 1], o1);
        }

        float x0v[8];
        #pragma unroll
        for (int k = 0; k < 8; ++k)
            x0v[k] = fmaf(xr[k], input_std[k], input_mean[k]);
        const float px = x0v[0], py = x0v[1], th = x0v[2], v = x0v[3];
        const float opx = x0v[4], opy = x0v[5], oth = x0v[6], ov = x0v[7];

        float st, ct, sto, cto;
        sincosf(th,  &st,  &ct);
        sincosf(oth, &sto, &cto);

        const float tvs = 2.0f * v * st;
        const float tvc = 2.0f * v * ct;
        const float tc  = 2.0f * ct;
        const float ts  = 2.0f * st;
        const float hc  = 2.0f * v * v;

        const float dxo = px - opx, dyo = py - opy;

        if (role == 0) {
            const float A0  = px * tvs - py * tvc;
            const float A1  = -(px * tc + py * ts);
            const float Go0 = dxo * tvs - dyo * tvc;
            const float Go1 = -(dxo * tc + dyo * ts);
            *(f32x4*)&prm[l][0] = (f32x4){A0, tvs, tvc, A1};
            *(f32x4*)&prm[l][4] = (f32x4){tc, ts, o0, o1};
            *(f32x2*)&prm[l][8] = (f32x2){Go0, Go1};
        } else {
            const float p0 = 4.0f / (1.0f + __expf(-o0));
            const float p1 = 4.0f / (1.0f + __expf(-o1));
            const float ps = p0 + p1;
            const float pp = p0 * p1;
            const float B0 = px * tvc + py * tvs;
            const float C  = hc + ps * B0 + pp * (px * px + py * py);
            const float u  = -(ps * tvc) - 2.0f * pp * px;
            const float w  = -(ps * tvs) - 2.0f * pp * py;
            const float ob  = dxo * dxo + dyo * dyo - 1.21f;     // Ro^2
            const float rvx = v * ct - ov * cto;
            const float rvy = v * st - ov * sto;
            const float obd = 2.0f * (dxo * rvx + dyo * rvy);
            const float cth_sum = ct * cto - st * sto;            // cos(th+oth)
            const float oLf2b = 2.0f * (v * v + ov * ov - 2.0f * v * ov * cth_sum);
            const float ho = oLf2b + ps * obd + pp * ob;
            *(f32x2*)&prm[l][10]  = (f32x2){ho, 0.0f};
            *(f32x4*)&prm[l][12]  = (f32x4){C, u, w, pp};
        }
    }
    __syncthreads();

    // ======================= Phase B: one phase per wave ====================
    const int blockRow0 = blockIdx.x * 64;
    if      (wv == 0) phase_rows<0>(blockRow0, l, prm, obstacles, out);
    else if (wv == 1) phase_rows<1>(blockRow0, l, prm, obstacles, out);
    else if (wv == 2) phase_rows<2>(blockRow0, l, prm, obstacles, out);
    else              phase_rows<3>(blockRow0, l, prm, obstacles, out);
}

extern "C" void kernel_launch(void* const* d_in, const int* in_sizes, int n_in,
                              void* d_out, int out_size, void* d_ws, size_t ws_size,
                              hipStream_t stream) {
    const float* x          = (const float*)d_in[0];
    const float* obstacles  = (const float*)d_in[1];
    const float* input_mean = (const float*)d_in[2];
    const float* input_std  = (const float*)d_in[3];
    const float* W1  = (const float*)d_in[4];
    const float* b1  = (const float*)d_in[5];
    const float* W21 = (const float*)d_in[6];
    const float* b21 = (const float*)d_in[7];
    const float* W22 = (const float*)d_in[8];
    const float* b22 = (const float*)d_in[9];
    const float* W31 = (const float*)d_in[10];
    const float* b31 = (const float*)d_in[11];
    const float* W32 = (const float*)d_in[12];
    const float* b32 = (const float*)d_in[13];

    float* out = (float*)d_out;

    fused4<<<dim3(NB_TOTAL / 64), dim3(256), 0, stream>>>(
        x, obstacles, input_mean, input_std,
        W1, b1, W21, b21, W22, b22, W31, b31, W32, b32, out);
}